// Round 1
// baseline (872.946 us; speedup 1.0000x reference)
//
#include <hip/hip_runtime.h>

// sizes: B=8, N=5, C=256, H*W=4096, PIX = 32768 global pixels
typedef __attribute__((ext_vector_type(8))) short short8;
typedef __attribute__((ext_vector_type(4))) float f32x4;
typedef __attribute__((ext_vector_type(8))) unsigned short us8;
typedef __attribute__((ext_vector_type(4))) unsigned short us4;
typedef __attribute__((ext_vector_type(2))) unsigned short us2;

__device__ __forceinline__ float sigmoidf_(float x){ return 1.f/(1.f+__expf(-x)); }
__device__ __forceinline__ unsigned short f2bf(float f){
    union{float f; unsigned int u;} x; x.f = f;
    unsigned int r = x.u + 0x7fffu + ((x.u>>16)&1u);
    return (unsigned short)(r>>16);
}
__device__ __forceinline__ float bf2f(unsigned short u){
    union{unsigned int u; float f;} x; x.u = ((unsigned int)u)<<16; return x.f;
}
#define GAS(p) ((const __attribute__((address_space(1))) void*)(uintptr_t)(p))
#define LAS(p) ((__attribute__((address_space(3))) void*)(uintptr_t)(p))

#define SLOT 8388608ull   // per-slot stride in ushorts (and in floats for nothing else)

// D[b][n][j][pl] = sum_c inputs[b,n,c,pl] * wgt_w[j,c]
__global__ __launch_bounds__(256) void k_dots(const float* __restrict__ inp, const float* __restrict__ wgt,
                                              float* __restrict__ D){
    __shared__ float wg[1024];
    for (int s=threadIdx.x; s<1024; s+=256) wg[s] = wgt[s];
    __syncthreads();
    int e = blockIdx.x*256 + threadIdx.x;
    int pl = e & 4095;
    int bn = e >> 12;
    const float* base = inp + (((size_t)bn*256)<<12) + pl;
    float d0=0,d1=0,d2=0,d3=0;
    #pragma unroll 8
    for (int c=0;c<256;c++){
        float v = base[(size_t)c<<12];
        d0 += v*wg[c]; d1 += v*wg[256+c]; d2 += v*wg[512+c]; d3 += v*wg[768+c];
    }
    size_t o = ((size_t)bn*4)<<12;
    D[o+pl]=d0; D[o+4096+pl]=d1; D[o+8192+pl]=d2; D[o+12288+pl]=d3;
}

// Weight prep, both matrices in one launch.
// dst blocked [kb][OCN][64] bf16 from fp32 [oc][512] rows.
__global__ __launch_bounds__(256) void k_wp2(const float* __restrict__ w_u, const float* __restrict__ w_r,
                                             const float* __restrict__ w_o,
                                             unsigned short* __restrict__ Wc0, unsigned short* __restrict__ Wc1){
    int bx = blockIdx.x;
    const float *s0, *s1; unsigned short* dst; int OCN, tid;
    if (bx < 256){ tid = bx*256 + threadIdx.x; OCN = 512; s0 = w_u; s1 = w_r; dst = Wc0; }
    else         { tid = (bx-256)*256 + threadIdx.x; OCN = 256; s0 = w_o; s1 = w_o; dst = Wc1; }
    int d = tid*4;
    int kk = d & 63;
    int row = d >> 6;
    int oc = row & (OCN-1);
    int kb = row / OCN;
    int k  = kb*64 + kk;
    const float* src = (oc < 256) ? s0 : s1;
    int ocr = (oc < 256) ? oc : oc-256;
    float4 v = *(const float4*)&src[(size_t)ocr*512 + k];
    us4 pk; pk.x=f2bf(v.x); pk.y=f2bf(v.y); pk.z=f2bf(v.z); pk.w=f2bf(v.w);
    *(us4*)&dst[d] = pk;
}

// Fused: per block (64c x 32p tile), load all 5 n-slices once (registers),
// S = sum_n in-register, gate = sigmoid(D_i - D_node) inline, then per slot i:
// m_t = g*(S-x_i) and h_t = x_i, bf16, transposed through LDS -> blocked [kb][p][64].
// grid: 4 c-tiles x 1024 p-tiles = 4096 blocks.
__global__ __launch_bounds__(256) void k_bxs(const float* __restrict__ inp, const float* __restrict__ D,
                                             unsigned short* __restrict__ Alo, unsigned short* __restrict__ Ahi,
                                             int i0, int cnt){
    __shared__ unsigned short tm[64*34];   // stride 34 us = 17 words (odd) -> 4-way read conflicts max
    __shared__ unsigned short th[64*34];
    int t  = threadIdx.x;
    int c0 = (blockIdx.x & 3) << 6;
    int pz = blockIdx.x >> 2;
    int p0 = pz << 5;
    int b  = p0 >> 12, pl0 = p0 & 4095;

    f32x4 x[5][2], S4[2];
    #pragma unroll
    for (int q=0;q<2;q++){
        int s = t + q*256;
        int c = s >> 3, pc = (s&7) << 2;
        int cc = c0 + c;
        f32x4 acc = {0.f,0.f,0.f,0.f};
        #pragma unroll
        for (int n=0;n<5;n++){
            x[n][q] = *(const f32x4*)&inp[(((size_t)((b*5+n)*256+cc))<<12) + pl0 + pc];
            acc += x[n][q];
        }
        S4[q] = acc;
    }
    int kb = c0 >> 6;
    #pragma unroll
    for (int i=0;i<5;i++){
        if (i < i0 || i >= i0+cnt) continue;
        #pragma unroll
        for (int q=0;q<2;q++){
            int s = t + q*256;
            int c = s >> 3, pc = (s&7) << 2;
            int j = c & 3;
            int node = (j < i) ? j : (j+1);
            f32x4 dw = *(const f32x4*)&D[(((size_t)((b*5+i)*4+j))<<12) + pl0 + pc];
            f32x4 dn = *(const f32x4*)&D[(((size_t)((b*5+node)*4+j))<<12) + pl0 + pc];
            f32x4 xi = x[i][q];
            f32x4 md = S4[q] - xi;
            int lb = c*34 + pc;
            us2 m0, m1, h0, h1;
            m0.x = f2bf(sigmoidf_(dw.x-dn.x)*md.x); m0.y = f2bf(sigmoidf_(dw.y-dn.y)*md.y);
            m1.x = f2bf(sigmoidf_(dw.z-dn.z)*md.z); m1.y = f2bf(sigmoidf_(dw.w-dn.w)*md.w);
            h0.x = f2bf(xi.x); h0.y = f2bf(xi.y); h1.x = f2bf(xi.z); h1.y = f2bf(xi.w);
            *(us2*)&tm[lb] = m0; *(us2*)&tm[lb+2] = m1;
            *(us2*)&th[lb] = h0; *(us2*)&th[lb+2] = h1;
        }
        __syncthreads();
        {
            int p = t >> 3, cs = (t&7) << 3;
            us8 vm, vh;
            #pragma unroll
            for (int j8=0;j8<8;j8++){ vm[j8] = tm[(cs+j8)*34 + p]; vh[j8] = th[(cs+j8)*34 + p]; }
            size_t dst = (size_t)(i - i0)*SLOT + ((size_t)kb*32768 + p0 + p)*64 + cs;
            *(us8*)&Alo[dst] = vm;
            *(us8*)&Ahi[dst] = vh;
        }
        __syncthreads();
    }
}

// MFMA GEMM: D[oc][p] = sum_k W[oc][k]*Act[p][k]. Tile 128oc x 128p, BK=64, 4 waves.
// z-dim = slot within group; slot i = i0 + z.
// EPI0 (OCN=512): oc<256 -> U[oc][p] = bf16(sigmoid(v+b_u));
//                 oc>=256 -> A1hi = bf16(sigmoid(v+b_r) * h_bf16-from-Ahi)
// EPI1 (OCN=256): out = (h*(1-u)+tanh(v+b_o)*u)*gamma + h
template<int EPI>
__global__ __launch_bounds__(256) void k_mm(
        const unsigned short* __restrict__ Alo, const unsigned short* __restrict__ Ahi,
        const unsigned short* __restrict__ Wb,
        const float* __restrict__ inp, const float* __restrict__ b0, const float* __restrict__ b1,
        unsigned short* __restrict__ U, unsigned short* __restrict__ A1hi, float* __restrict__ outp,
        const float* __restrict__ gamma_p, int i0)
{
    constexpr int OCN = EPI ? 256 : 512;
    __shared__ unsigned short As[128*64];   // weights tile [oc][64]
    __shared__ unsigned short Bs[128*64];   // pixel tile  [p][64]
    int t  = threadIdx.x, wv = t>>6, ln = t&63;
    int p0 = blockIdx.x*128, oc0 = blockIdx.y*128;
    int z  = blockIdx.z, i = i0 + z;
    size_t zo = (size_t)z*SLOT;
    int wm = (wv>>1)*64, wn = (wv&1)*64;
    int row = ln & 15, quad = ln >> 4, kq = quad*8;

    f32x4 acc[4][4];
    f32x4 zr = {0.f,0.f,0.f,0.f};
    #pragma unroll
    for (int a=0;a<4;a++){
        #pragma unroll
        for (int o=0;o<4;o++) acc[a][o]=zr;
    }

    for (int kb=0; kb<8; ++kb){
        const unsigned short* gA = (kb<4) ? (Alo + zo + ((size_t)kb*32768 + p0)*64)
                                          : (Ahi + zo + ((size_t)(kb-4)*32768 + p0)*64);
        const unsigned short* gW = Wb + ((size_t)kb*OCN + oc0)*64;
        #pragma unroll
        for (int q=0;q<4;q++){
            int off = (wv*4+q)*512;      // ushort units, 1024B chunks
            __builtin_amdgcn_global_load_lds(GAS(gA + off + ln*8), LAS(Bs + off + ln*8), 16, 0, 0);
            __builtin_amdgcn_global_load_lds(GAS(gW + off + ln*8), LAS(As + off + ln*8), 16, 0, 0);
        }
        __syncthreads();
        #pragma unroll
        for (int ks=0; ks<2; ks++){
            short8 a[4], b[4];
            #pragma unroll
            for (int f=0; f<4; f++){
                a[f] = *(const short8*)&As[(wm+f*16+row)*64 + ks*32 + kq];
                b[f] = *(const short8*)&Bs[(wn+f*16+row)*64 + ks*32 + kq];
            }
            #pragma unroll
            for (int fm=0; fm<4; fm++){
                #pragma unroll
                for (int fn=0; fn<4; fn++)
                    acc[fm][fn] = __builtin_amdgcn_mfma_f32_16x16x32_bf16(a[fm], b[fn], acc[fm][fn], 0,0,0);
            }
        }
        __syncthreads();
    }

    float gm = EPI ? gamma_p[0] : 0.f;
    #pragma unroll
    for (int fn=0; fn<4; fn++){
        int p  = p0 + wn + fn*16 + row;
        int b  = p >> 12, pl = p & 4095;
        size_t hb = (((size_t)((b*5+i)*256))<<12) + pl;
        #pragma unroll
        for (int fm=0; fm<4; fm++){
            int ocb = oc0 + wm + fm*16 + quad*4;
            if (EPI==0){
                if (oc0 < 256){
                    #pragma unroll
                    for (int r=0;r<4;r++){
                        int oc = ocb + r;
                        U[zo + (size_t)oc*32768 + p] = f2bf(sigmoidf_(acc[fm][fn][r] + b0[oc]));
                    }
                } else {
                    int kb2 = ocb - 256;             // mult of 4
                    size_t aidx = zo + ((size_t)(kb2>>6)*32768 + p)*64 + (kb2&63);
                    us4 vh = *(const us4*)&Ahi[aidx];
                    us4 pk;
                    #pragma unroll
                    for (int r=0;r<4;r++){
                        float rg = sigmoidf_(acc[fm][fn][r] + b1[kb2+r]);
                        pk[r] = f2bf(rg * bf2f(vh[r]));
                    }
                    *(us4*)&A1hi[aidx] = pk;
                }
            } else {
                #pragma unroll
                for (int r=0;r<4;r++){
                    int oc = ocb + r;
                    float v  = acc[fm][fn][r] + b0[oc];
                    float e2 = __expf(2.f*v);
                    float thv = 1.f - 2.f/(e2+1.f);
                    float u  = bf2f(U[zo + (size_t)oc*32768 + p]);
                    float h  = inp[hb + ((size_t)oc<<12)];
                    float hn = h*(1.f-u) + thv*u;
                    outp[hb + ((size_t)oc<<12)] = hn*gm + h;
                }
            }
        }
    }
}

extern "C" void kernel_launch(void* const* d_in, const int* in_sizes, int n_in,
                              void* d_out, int out_size, void* d_ws, size_t ws_size,
                              hipStream_t stream) {
    const float* inputs = (const float*)d_in[0];
    const float* wgt_w  = (const float*)d_in[1];
    const float* w_r    = (const float*)d_in[2];
    const float* b_r    = (const float*)d_in[3];
    const float* w_u    = (const float*)d_in[4];
    const float* b_u    = (const float*)d_in[5];
    const float* w_o    = (const float*)d_in[6];
    const float* b_o    = (const float*)d_in[7];
    const float* gamma  = (const float*)d_in[8];
    float* out = (float*)d_out;

    float* D = (float*)d_ws;                              // 655360 f
    unsigned short* Wc0 = (unsigned short*)(D + 655360);  // 512*512
    unsigned short* Wc1 = Wc0 + 262144;                   // 256*512
    unsigned short* U   = Wc1 + 131072;                   // nb slots x 8388608 (bf16)

    size_t fixedB = 655360ull*4 + (262144ull + 131072ull)*2;
    size_t slotB  = 4ull*SLOT*2;                          // U + Alo + Ahi + A1hi per slot
    int nb = 1;
    for (int k2=5;k2>=1;k2--){ if (fixedB + (size_t)k2*slotB <= ws_size){ nb = k2; break; } }

    unsigned short* Alo  = U   + (size_t)nb*SLOT;         // m_t blocked
    unsigned short* Ahi  = Alo + (size_t)nb*SLOT;         // h_t blocked
    unsigned short* A1hi = Ahi + (size_t)nb*SLOT;         // h*r blocked

    k_dots<<<640, 256, 0, stream>>>(inputs, wgt_w, D);
    k_wp2 <<<384, 256, 0, stream>>>(w_u, w_r, w_o, Wc0, Wc1);
    for (int i0=0; i0<5; i0+=nb){
        int cnt = (5-i0 < nb) ? (5-i0) : nb;
        k_bxs<<<4096, 256, 0, stream>>>(inputs, D, Alo, Ahi, i0, cnt);
        k_mm<0><<<dim3(256,4,cnt), 256, 0, stream>>>(Alo, Ahi, Wc0, inputs, b_u, b_r,
                                                     U, A1hi, nullptr, gamma, i0);
        k_mm<1><<<dim3(256,2,cnt), 256, 0, stream>>>(Alo, A1hi, Wc1, inputs, b_o, nullptr,
                                                     U, nullptr, out, gamma, i0);
    }
}

// Round 2
// 707.558 us; speedup vs baseline: 1.2337x; 1.2337x over previous
//
#include <hip/hip_runtime.h>

// sizes: B=8, N=5, C=256, H*W=4096, PIX = 32768 global pixels
typedef __attribute__((ext_vector_type(8))) short short8;
typedef __attribute__((ext_vector_type(4))) float f32x4;
typedef __attribute__((ext_vector_type(8))) unsigned short us8;
typedef __attribute__((ext_vector_type(4))) unsigned short us4;
typedef __attribute__((ext_vector_type(2))) unsigned short us2;

__device__ __forceinline__ float sigmoidf_(float x){ return 1.f/(1.f+__expf(-x)); }
__device__ __forceinline__ unsigned short f2bf(float f){
    union{float f; unsigned int u;} x; x.f = f;
    unsigned int r = x.u + 0x7fffu + ((x.u>>16)&1u);
    return (unsigned short)(r>>16);
}
__device__ __forceinline__ float bf2f(unsigned short u){
    union{unsigned int u; float f;} x; x.u = ((unsigned int)u)<<16; return x.f;
}
#define GAS(p) ((const __attribute__((address_space(1))) void*)(uintptr_t)(p))
#define LAS(p) ((__attribute__((address_space(3))) void*)(uintptr_t)(p))

#define SLOT 8388608ull   // per-slot stride in ushorts

// D[b][n][j][pl] = sum_c inputs[b,n,c,pl] * wgt_w[j,c]
__global__ __launch_bounds__(256) void k_dots(const float* __restrict__ inp, const float* __restrict__ wgt,
                                              float* __restrict__ D){
    __shared__ float wg[1024];
    for (int s=threadIdx.x; s<1024; s+=256) wg[s] = wgt[s];
    __syncthreads();
    int e = blockIdx.x*256 + threadIdx.x;
    int pl = e & 4095;
    int bn = e >> 12;
    const float* base = inp + (((size_t)bn*256)<<12) + pl;
    float d0=0,d1=0,d2=0,d3=0;
    #pragma unroll 8
    for (int c=0;c<256;c++){
        float v = base[(size_t)c<<12];
        d0 += v*wg[c]; d1 += v*wg[256+c]; d2 += v*wg[512+c]; d3 += v*wg[768+c];
    }
    size_t o = ((size_t)bn*4)<<12;
    D[o+pl]=d0; D[o+4096+pl]=d1; D[o+8192+pl]=d2; D[o+12288+pl]=d3;
}

// Weight prep, both matrices in one launch.
// dst blocked [kb][OCN][64] bf16, chunk-XOR-swizzled: the 16B chunk index (bits 5:3
// of the k-offset) is XORed with (oc&7) so mm's ds_read_b128 is bank-conflict-free.
__global__ __launch_bounds__(256) void k_wp2(const float* __restrict__ w_u, const float* __restrict__ w_r,
                                             const float* __restrict__ w_o,
                                             unsigned short* __restrict__ Wc0, unsigned short* __restrict__ Wc1){
    int bx = blockIdx.x;
    const float *s0, *s1; unsigned short* dst; int OCN, tid;
    if (bx < 256){ tid = bx*256 + threadIdx.x; OCN = 512; s0 = w_u; s1 = w_r; dst = Wc0; }
    else         { tid = (bx-256)*256 + threadIdx.x; OCN = 256; s0 = w_o; s1 = w_o; dst = Wc1; }
    int d = tid*4;
    int kk = d & 63;
    int row = d >> 6;
    int oc = row & (OCN-1);
    int kb = row / OCN;
    int k  = kb*64 + kk;
    const float* src = (oc < 256) ? s0 : s1;
    int ocr = (oc < 256) ? oc : oc-256;
    float4 v = *(const float4*)&src[(size_t)ocr*512 + k];
    us4 pk; pk.x=f2bf(v.x); pk.y=f2bf(v.y); pk.z=f2bf(v.z); pk.w=f2bf(v.w);
    int kk_sw = kk ^ ((oc&7)<<3);
    *(us4*)&dst[(size_t)row*64 + kk_sw] = pk;
}

// Fused: per block (64c x 32p tile), load all 5 n-slices once (registers),
// S = sum_n in-register, gate = sigmoid(D_i - D_node) inline, then per slot i:
// m_t = g*(S-x_i) and h_t = x_i, bf16, transposed through LDS -> blocked [kb][p][64],
// chunk-XOR-swizzled by (p&7).
__global__ __launch_bounds__(256) void k_bxs(const float* __restrict__ inp, const float* __restrict__ D,
                                             unsigned short* __restrict__ Alo, unsigned short* __restrict__ Ahi,
                                             int i0, int cnt){
    __shared__ unsigned short tm[64*34];
    __shared__ unsigned short th[64*34];
    int t  = threadIdx.x;
    int c0 = (blockIdx.x & 3) << 6;
    int pz = blockIdx.x >> 2;
    int p0 = pz << 5;
    int b  = p0 >> 12, pl0 = p0 & 4095;

    f32x4 x[5][2], S4[2];
    #pragma unroll
    for (int q=0;q<2;q++){
        int s = t + q*256;
        int c = s >> 3, pc = (s&7) << 2;
        int cc = c0 + c;
        f32x4 acc = {0.f,0.f,0.f,0.f};
        #pragma unroll
        for (int n=0;n<5;n++){
            x[n][q] = *(const f32x4*)&inp[(((size_t)((b*5+n)*256+cc))<<12) + pl0 + pc];
            acc += x[n][q];
        }
        S4[q] = acc;
    }
    int kb = c0 >> 6;
    #pragma unroll
    for (int i=0;i<5;i++){
        if (i < i0 || i >= i0+cnt) continue;
        #pragma unroll
        for (int q=0;q<2;q++){
            int s = t + q*256;
            int c = s >> 3, pc = (s&7) << 2;
            int j = c & 3;
            int node = (j < i) ? j : (j+1);
            f32x4 dw = *(const f32x4*)&D[(((size_t)((b*5+i)*4+j))<<12) + pl0 + pc];
            f32x4 dn = *(const f32x4*)&D[(((size_t)((b*5+node)*4+j))<<12) + pl0 + pc];
            f32x4 xi = x[i][q];
            f32x4 md = S4[q] - xi;
            int lb = c*34 + pc;
            us2 m0, m1, h0, h1;
            m0.x = f2bf(sigmoidf_(dw.x-dn.x)*md.x); m0.y = f2bf(sigmoidf_(dw.y-dn.y)*md.y);
            m1.x = f2bf(sigmoidf_(dw.z-dn.z)*md.z); m1.y = f2bf(sigmoidf_(dw.w-dn.w)*md.w);
            h0.x = f2bf(xi.x); h0.y = f2bf(xi.y); h1.x = f2bf(xi.z); h1.y = f2bf(xi.w);
            *(us2*)&tm[lb] = m0; *(us2*)&tm[lb+2] = m1;
            *(us2*)&th[lb] = h0; *(us2*)&th[lb+2] = h1;
        }
        __syncthreads();
        {
            int p = t >> 3, cs = (t&7) << 3;
            us8 vm, vh;
            #pragma unroll
            for (int j8=0;j8<8;j8++){ vm[j8] = tm[(cs+j8)*34 + p]; vh[j8] = th[(cs+j8)*34 + p]; }
            int cs_sw = cs ^ ((p&7)<<3);
            size_t dst = (size_t)(i - i0)*SLOT + ((size_t)kb*32768 + p0 + p)*64 + cs_sw;
            *(us8*)&Alo[dst] = vm;
            *(us8*)&Ahi[dst] = vh;
        }
        __syncthreads();
    }
}

// MFMA GEMM: D[oc][p] = sum_k W[oc][k]*Act[p][k]. Tile 128oc x 128p, BK=64, 4 waves,
// double-buffered LDS with STAGE-early (T3 minimum 2-phase recipe):
//   stage(t+1) issued BEFORE compute(t); single __syncthreads (full drain) per step.
// Grid x encodes (p_tile, oc_tile) XCD-chunked, oc-fast, so same-A oc-tiles run
// temporally adjacent on one XCD L2; z = slot.
// Blocked operands are chunk-XOR-swizzled (producer side); ds_reads apply the XOR.
// EPI0 (OCN=512): oc<256 -> U[p][oc] = bf16(sigmoid(v+b_u))  (p-major, us4-coalesced)
//                 oc>=256 -> A1hi = bf16(sigmoid(v+b_r) * h_bf16-from-Ahi)
// EPI1 (OCN=256): out = (h*(1-u)+tanh(v+b_o)*u)*gamma + h
template<int EPI>
__global__ __launch_bounds__(256) void k_mm(
        const unsigned short* __restrict__ Alo, const unsigned short* __restrict__ Ahi,
        const unsigned short* __restrict__ Wb,
        const float* __restrict__ inp, const float* __restrict__ b0, const float* __restrict__ b1,
        unsigned short* __restrict__ U, unsigned short* __restrict__ A1hi, float* __restrict__ outp,
        const float* __restrict__ gamma_p, int i0)
{
    constexpr int OCN = EPI ? 256 : 512;
    constexpr int NY  = EPI ? 2   : 4;      // oc tiles
    constexpr int NWG = 256*NY;             // p tiles = 256
    __shared__ unsigned short As[2][128*64];   // weights tile [oc][64]
    __shared__ unsigned short Bs[2][128*64];   // pixel tile  [p][64]
    int t  = threadIdx.x, wv = t>>6, ln = t&63;

    // XCD-chunked remap, oc-fast within chunk
    int bid = blockIdx.x;
    int wg  = (bid&7)*(NWG>>3) + (bid>>3);
    int oc0 = (wg & (NY-1)) * 128;
    int p0  = (wg / NY) * 128;

    int z  = blockIdx.z, i = i0 + z;
    size_t zo = (size_t)z*SLOT;
    int wm = (wv>>1)*64, wn = (wv&1)*64;
    int row = ln & 15, quad = ln >> 4, kq = quad*8;

    f32x4 acc[4][4];
    f32x4 zr = {0.f,0.f,0.f,0.f};
    #pragma unroll
    for (int a=0;a<4;a++){
        #pragma unroll
        for (int o=0;o<4;o++) acc[a][o]=zr;
    }

    auto stage = [&](int kb, int buf){
        const unsigned short* gA = (kb<4) ? (Alo + zo + ((size_t)kb*32768 + p0)*64)
                                          : (Ahi + zo + ((size_t)(kb-4)*32768 + p0)*64);
        const unsigned short* gW = Wb + ((size_t)kb*OCN + oc0)*64;
        #pragma unroll
        for (int q=0;q<4;q++){
            int off = (wv*4+q)*512;      // ushort units, 1024B chunks
            __builtin_amdgcn_global_load_lds(GAS(gA + off + ln*8), LAS(&Bs[buf][off + ln*8]), 16, 0, 0);
            __builtin_amdgcn_global_load_lds(GAS(gW + off + ln*8), LAS(&As[buf][off + ln*8]), 16, 0, 0);
        }
    };

    stage(0, 0);
    __syncthreads();                 // drains vmcnt -> buf0 ready

    int rsw = (row&7)<<3;            // chunk-XOR for this lane's rows
    for (int kb=0; kb<8; ++kb){
        int cur = kb & 1;
        if (kb < 7) stage(kb+1, cur^1);
        #pragma unroll
        for (int ks=0; ks<2; ks++){
            short8 a[4], b[4];
            int col = (ks*32 + kq) ^ rsw;
            #pragma unroll
            for (int f=0; f<4; f++){
                a[f] = *(const short8*)&As[cur][(wm+f*16+row)*64 + col];
                b[f] = *(const short8*)&Bs[cur][(wn+f*16+row)*64 + col];
            }
            __builtin_amdgcn_s_setprio(1);
            #pragma unroll
            for (int fm=0; fm<4; fm++){
                #pragma unroll
                for (int fn=0; fn<4; fn++)
                    acc[fm][fn] = __builtin_amdgcn_mfma_f32_16x16x32_bf16(a[fm], b[fn], acc[fm][fn], 0,0,0);
            }
            __builtin_amdgcn_s_setprio(0);
        }
        __syncthreads();             // drains next-tile loads; frees cur for kb+2 stage
    }

    float gm = EPI ? gamma_p[0] : 0.f;
    #pragma unroll
    for (int fn=0; fn<4; fn++){
        int p  = p0 + wn + fn*16 + row;
        int b  = p >> 12, pl = p & 4095;
        size_t hb = (((size_t)((b*5+i)*256))<<12) + pl;
        #pragma unroll
        for (int fm=0; fm<4; fm++){
            int ocb = oc0 + wm + fm*16 + quad*4;
            if (EPI==0){
                if (oc0 < 256){
                    us4 pk;
                    #pragma unroll
                    for (int r=0;r<4;r++)
                        pk[r] = f2bf(sigmoidf_(acc[fm][fn][r] + b0[ocb+r]));
                    *(us4*)&U[zo + (size_t)p*256 + ocb] = pk;   // p-major
                } else {
                    int kb2 = ocb - 256;             // mult of 4
                    int kc  = (kb2&63) ^ ((p&7)<<3); // producer-side swizzle
                    size_t aidx = zo + ((size_t)(kb2>>6)*32768 + p)*64 + kc;
                    us4 vh = *(const us4*)&Ahi[aidx];
                    us4 pk;
                    #pragma unroll
                    for (int r=0;r<4;r++){
                        float rg = sigmoidf_(acc[fm][fn][r] + b1[kb2+r]);
                        pk[r] = f2bf(rg * bf2f(vh[r]));
                    }
                    *(us4*)&A1hi[aidx] = pk;
                }
            } else {
                us4 vu = *(const us4*)&U[zo + (size_t)p*256 + ocb];
                #pragma unroll
                for (int r=0;r<4;r++){
                    int oc = ocb + r;
                    float v  = acc[fm][fn][r] + b0[oc];
                    float e2 = __expf(2.f*v);
                    float thv = 1.f - 2.f/(e2+1.f);
                    float u  = bf2f(vu[r]);
                    float h  = inp[hb + ((size_t)oc<<12)];
                    float hn = h*(1.f-u) + thv*u;
                    outp[hb + ((size_t)oc<<12)] = hn*gm + h;
                }
            }
        }
    }
}

extern "C" void kernel_launch(void* const* d_in, const int* in_sizes, int n_in,
                              void* d_out, int out_size, void* d_ws, size_t ws_size,
                              hipStream_t stream) {
    const float* inputs = (const float*)d_in[0];
    const float* wgt_w  = (const float*)d_in[1];
    const float* w_r    = (const float*)d_in[2];
    const float* b_r    = (const float*)d_in[3];
    const float* w_u    = (const float*)d_in[4];
    const float* b_u    = (const float*)d_in[5];
    const float* w_o    = (const float*)d_in[6];
    const float* b_o    = (const float*)d_in[7];
    const float* gamma  = (const float*)d_in[8];
    float* out = (float*)d_out;

    float* D = (float*)d_ws;                              // 655360 f
    unsigned short* Wc0 = (unsigned short*)(D + 655360);  // 512*512
    unsigned short* Wc1 = Wc0 + 262144;                   // 256*512
    unsigned short* U   = Wc1 + 131072;                   // nb slots x 8388608 (bf16)

    size_t fixedB = 655360ull*4 + (262144ull + 131072ull)*2;
    size_t slotB  = 4ull*SLOT*2;                          // U + Alo + Ahi + A1hi per slot
    int nb = 1;
    for (int k2=5;k2>=1;k2--){ if (fixedB + (size_t)k2*slotB <= ws_size){ nb = k2; break; } }

    unsigned short* Alo  = U   + (size_t)nb*SLOT;         // m_t blocked
    unsigned short* Ahi  = Alo + (size_t)nb*SLOT;         // h_t blocked
    unsigned short* A1hi = Ahi + (size_t)nb*SLOT;         // h*r blocked

    k_dots<<<640, 256, 0, stream>>>(inputs, wgt_w, D);
    k_wp2 <<<384, 256, 0, stream>>>(w_u, w_r, w_o, Wc0, Wc1);
    for (int i0=0; i0<5; i0+=nb){
        int cnt = (5-i0 < nb) ? (5-i0) : nb;
        k_bxs<<<4096, 256, 0, stream>>>(inputs, D, Alo, Ahi, i0, cnt);
        k_mm<0><<<dim3(1024,1,cnt), 256, 0, stream>>>(Alo, Ahi, Wc0, inputs, b_u, b_r,
                                                      U, A1hi, nullptr, gamma, i0);
        k_mm<1><<<dim3(512,1,cnt), 256, 0, stream>>>(Alo, A1hi, Wc1, inputs, b_o, nullptr,
                                                     U, nullptr, out, gamma, i0);
    }
}